// Round 1
// baseline (90.014 us; speedup 1.0000x reference)
//
#include <hip/hip_runtime.h>
#include <math.h>

#define T_DIM 512
#define B_DIM 64
#define D_DIM 256
#define F_DIM 256
#define ALPHA 0.2f

// workspace layout (in floats)
#define U_OFF 0
#define V_OFF 256
#define P_OFF 512
#define Q_OFF (512 + 32768)
#define C_OFF (512 + 2*32768)
#define Z_OFF (512 + 3*32768)
#define WS_FLOATS (512 + 3*32768 + 16384)

__device__ __forceinline__ float lrelu(float x) {
    return fmaxf(x, ALPHA * x);
}

// Kernel A: u = W @ a1, v = W @ a2  (D-vectors). One block, 256 threads.
__global__ void k_uv(const float* __restrict__ W, const float* __restrict__ a1,
                     const float* __restrict__ a2, float* __restrict__ ws) {
    __shared__ float s1[F_DIM], s2[F_DIM];
    int tid = threadIdx.x;
    s1[tid] = a1[tid];
    s2[tid] = a2[tid];
    __syncthreads();
    const float4* Wrow = (const float4*)(W + (size_t)tid * F_DIM);
    float acc1 = 0.f, acc2 = 0.f;
    for (int f4 = 0; f4 < F_DIM / 4; ++f4) {
        float4 wv = Wrow[f4];
        int f = f4 * 4;
        acc1 += wv.x * s1[f] + wv.y * s1[f + 1] + wv.z * s1[f + 2] + wv.w * s1[f + 3];
        acc2 += wv.x * s2[f] + wv.y * s2[f + 1] + wv.z * s2[f + 2] + wv.w * s2[f + 3];
    }
    ws[U_OFF + tid] = acc1;
    ws[V_OFF + tid] = acc2;
}

// Kernel B: p[b,t] = x[b,t]·u, q[b,t] = x[b,t]·v.
// One wave per row r = t*B + b; 4 waves (4 rows) per 256-thread block.
__global__ void k_pq(const float* __restrict__ x, const int* __restrict__ turns,
                     float* __restrict__ ws) {
    int wave = threadIdx.x >> 6;
    int lane = threadIdx.x & 63;
    int r = blockIdx.x * 4 + wave;
    int t = r / B_DIM;
    int b = r % B_DIM;
    if (t > turns[b]) return;  // rows past turns never contribute (wave-uniform)
    const float4* row = (const float4*)(x + (size_t)r * D_DIM);
    const float4* u4 = (const float4*)(ws + U_OFF);
    const float4* v4 = (const float4*)(ws + V_OFF);
    float4 xv = row[lane];
    float4 uv = u4[lane];
    float4 vv = v4[lane];
    float pp = xv.x * uv.x + xv.y * uv.y + xv.z * uv.z + xv.w * uv.w;
    float qq = xv.x * vv.x + xv.y * vv.y + xv.z * vv.z + xv.w * vv.w;
    for (int off = 32; off > 0; off >>= 1) {
        pp += __shfl_down(pp, off);
        qq += __shfl_down(qq, off);
    }
    if (lane == 0) {
        ws[P_OFF + b * T_DIM + t] = pp;
        ws[Q_OFF + b * T_DIM + t] = qq;
    }
}

// Kernel C: per (b, w) attention column-sums -> accumulate x-row coefficients C[b,t].
// 192 blocks (b*3 + w-1), 512 threads.
__global__ __launch_bounds__(512) void k_attn(const int* __restrict__ turns,
                                              float* __restrict__ ws) {
    int b = blockIdx.x / 3;
    int w = (blockIdx.x % 3) + 1;
    int tn = turns[b];
    int cnt = tn - w + 2;
    if (cnt <= 0) return;        // has_w = 0, skip window (block-uniform)
    if (cnt > T_DIM) cnt = T_DIM;
    int tid = threadIdx.x;

    __shared__ float lp[T_DIM], lq[T_DIM], f1[T_DIM], f2[T_DIM];
    __shared__ float mi[T_DIM], ri[T_DIM], gg[T_DIM];
    __shared__ float red[8];

    lp[tid] = ws[P_OFF + b * T_DIM + tid];
    lq[tid] = ws[Q_OFF + b * T_DIM + tid];
    __syncthreads();

    float invw = 1.0f / (float)w;
    if (tid < cnt) {
        // tid + k <= cnt-1 + w-1 = turns <= 511, in-bounds
        float s1 = lp[tid], s2 = lq[tid];
        for (int k = 1; k < w; ++k) { s1 += lp[tid + k]; s2 += lq[tid + k]; }
        f1[tid] = s1 * invw;
        f2[tid] = s2 * invw;
    } else {
        f2[tid] = -3.0e38f;
    }
    __syncthreads();

    // block max of f2 over valid entries (invalid filled with -3e38)
    float m = f2[tid];
    for (int off = 32; off > 0; off >>= 1) m = fmaxf(m, __shfl_down(m, off));
    if ((tid & 63) == 0) red[tid >> 6] = m;
    __syncthreads();
    if (tid == 0) {
        float mm = red[0];
        for (int i = 1; i < 8; ++i) mm = fmaxf(mm, red[i]);
        red[0] = mm;
    }
    __syncthreads();
    float M = red[0];

    // Pass A: per-row softmax max (analytic, lrelu monotone) + inverse row sum
    if (tid < cnt) {
        float f1i = f1[tid];
        float mrow = lrelu(f1i + M);
        float r = 0.f;
        for (int j = 0; j < cnt; ++j) {
            float s = lrelu(f1i + f2[j]);
            r += __expf(s - mrow);
        }
        mi[tid] = mrow;
        ri[tid] = 1.0f / r;
    }
    __syncthreads();

    // Pass B: column sums g[j] = (1/cnt) * sum_i exp(s_ij - m_i) / r_i
    float invcnt = 1.0f / (float)cnt;
    if (tid < cnt) {
        float f2j = f2[tid];
        float g = 0.f;
        for (int i = 0; i < cnt; ++i) {
            float s = lrelu(f1[i] + f2j);
            g += __expf(s - mi[i]) * ri[i];
        }
        gg[tid] = g * invcnt;
    } else {
        gg[tid] = 0.f;
    }
    __syncthreads();

    // x-row coefficient: c_t = (1/w) * sum_{k=0..w-1} g[t-k], t-k in [0,cnt)
    float coef = 0.f;
    for (int k = 0; k < w; ++k) {
        int j = tid - k;
        if (j >= 0) coef += gg[j];  // gg[j]=0 for j>=cnt
    }
    coef *= invw;
    if (coef != 0.f) atomicAdd(&ws[C_OFF + b * T_DIM + tid], coef);
}

// Kernel D: Z[b,:] = sum_t C[b,t] * x[b,t,:].  Grid 64*8 blocks x 256 threads.
__global__ void k_z(const float* __restrict__ x, const int* __restrict__ turns,
                    float* __restrict__ ws) {
    int b = blockIdx.x >> 3;
    int chunk = blockIdx.x & 7;
    int tn = turns[b];
    int t0 = chunk * 64;
    if (t0 > tn) return;                 // coefficients are zero for t > turns
    int t1 = min(t0 + 64, tn + 1);
    int tid = threadIdx.x;  // d
    float acc = 0.f;
    for (int t = t0; t < t1; ++t) {
        float c = ws[C_OFF + b * T_DIM + t];
        acc += c * x[((size_t)t * B_DIM + b) * D_DIM + tid];
    }
    atomicAdd(&ws[Z_OFF + b * D_DIM + tid], acc);
}

// Kernel E: out[b,:] = (Z[b,:] @ W) / vws[b].  64 blocks x 256 threads.
__global__ void k_out(const float* __restrict__ W, const int* __restrict__ turns,
                      const float* __restrict__ ws, float* __restrict__ out) {
    int b = blockIdx.x;
    int tid = threadIdx.x;  // f
    __shared__ float zz[D_DIM];
    zz[tid] = ws[Z_OFF + b * D_DIM + tid];
    __syncthreads();
    float acc = 0.f;
#pragma unroll 4
    for (int d = 0; d < D_DIM; ++d)
        acc += zz[d] * W[(size_t)d * F_DIM + tid];
    int tn = turns[b];
    float vws = 1.0f + (tn >= 1 ? 1.0f : 0.0f) + (tn >= 2 ? 1.0f : 0.0f);
    out[b * F_DIM + tid] = acc / vws;
}

extern "C" void kernel_launch(void* const* d_in, const int* in_sizes, int n_in,
                              void* d_out, int out_size, void* d_ws, size_t ws_size,
                              hipStream_t stream) {
    const float* x = (const float*)d_in[0];     // (T,B,D) fp32
    const int* turns = (const int*)d_in[1];     // (B,) int32
    const float* W = (const float*)d_in[2];     // (D,F)
    const float* a1 = (const float*)d_in[3];    // (F,)
    const float* a2 = (const float*)d_in[4];    // (F,)
    float* out = (float*)d_out;                 // (B,F)
    float* ws = (float*)d_ws;

    hipMemsetAsync(d_ws, 0, WS_FLOATS * sizeof(float), stream);

    k_uv<<<1, 256, 0, stream>>>(W, a1, a2, ws);
    k_pq<<<(B_DIM * T_DIM) / 4, 256, 0, stream>>>(x, turns, ws);
    k_attn<<<B_DIM * 3, 512, 0, stream>>>(turns, ws);
    k_z<<<B_DIM * 8, 256, 0, stream>>>(x, turns, ws);
    k_out<<<B_DIM, 256, 0, stream>>>(W, turns, ws, out);
}

// Round 2
// 85.490 us; speedup vs baseline: 1.0529x; 1.0529x over previous
//
#include <hip/hip_runtime.h>
#include <math.h>

#define T_DIM 512
#define B_DIM 64
#define D_DIM 256
#define F_DIM 256
#define ALPHA 0.2f

// workspace layout (in floats) — every slot consumed is written every call;
// no pre-zeroing, no atomics.
#define U_OFF 0
#define V_OFF 256
#define P_OFF 512
#define Q_OFF (P_OFF + T_DIM * B_DIM)
#define C_OFF (Q_OFF + T_DIM * B_DIM)              // Cw[3][B][T]
#define ZP_OFF (C_OFF + 3 * B_DIM * T_DIM)         // Zp[B][8][D]

__device__ __forceinline__ float lrelu(float x) {
    return fmaxf(x, ALPHA * x);
}

// Kernel A: u = W @ a1, v = W @ a2  (D-vectors). One block, 256 threads.
__global__ void k_uv(const float* __restrict__ W, const float* __restrict__ a1,
                     const float* __restrict__ a2, float* __restrict__ ws) {
    __shared__ float s1[F_DIM], s2[F_DIM];
    int tid = threadIdx.x;
    s1[tid] = a1[tid];
    s2[tid] = a2[tid];
    __syncthreads();
    const float4* Wrow = (const float4*)(W + (size_t)tid * F_DIM);
    float acc1 = 0.f, acc2 = 0.f;
    for (int f4 = 0; f4 < F_DIM / 4; ++f4) {
        float4 wv = Wrow[f4];
        int f = f4 * 4;
        acc1 += wv.x * s1[f] + wv.y * s1[f + 1] + wv.z * s1[f + 2] + wv.w * s1[f + 3];
        acc2 += wv.x * s2[f] + wv.y * s2[f + 1] + wv.z * s2[f + 2] + wv.w * s2[f + 3];
    }
    ws[U_OFF + tid] = acc1;
    ws[V_OFF + tid] = acc2;
}

// Kernel B: p[b,t] = x[b,t]·u, q[b,t] = x[b,t]·v.
// One wave per row r = t*B + b; 4 waves (4 rows) per 256-thread block.
// Rows with t > turns[b] are never read downstream -> skip (wave-uniform).
__global__ void k_pq(const float* __restrict__ x, const int* __restrict__ turns,
                     float* __restrict__ ws) {
    int wave = threadIdx.x >> 6;
    int lane = threadIdx.x & 63;
    int r = blockIdx.x * 4 + wave;
    int t = r / B_DIM;
    int b = r % B_DIM;
    if (t > turns[b]) return;
    const float4* row = (const float4*)(x + (size_t)r * D_DIM);
    const float4* u4 = (const float4*)(ws + U_OFF);
    const float4* v4 = (const float4*)(ws + V_OFF);
    float4 xv = row[lane];
    float4 uv = u4[lane];
    float4 vv = v4[lane];
    float pp = xv.x * uv.x + xv.y * uv.y + xv.z * uv.z + xv.w * uv.w;
    float qq = xv.x * vv.x + xv.y * vv.y + xv.z * vv.z + xv.w * vv.w;
    for (int off = 32; off > 0; off >>= 1) {
        pp += __shfl_down(pp, off);
        qq += __shfl_down(qq, off);
    }
    if (lane == 0) {
        ws[P_OFF + b * T_DIM + t] = pp;
        ws[Q_OFF + b * T_DIM + t] = qq;
    }
}

// Kernel C: per (b, w) attention column-sums -> x-row coefficients
// Cw[w-1][b][t], written unconditionally (zeros when invalid).
// 192 blocks (b*3 + w-1), 512 threads.
__global__ __launch_bounds__(512) void k_attn(const int* __restrict__ turns,
                                              float* __restrict__ ws) {
    int b = blockIdx.x / 3;
    int w = (blockIdx.x % 3) + 1;
    int tn = turns[b];
    int cnt = tn - w + 2;
    if (cnt > T_DIM) cnt = T_DIM;
    int tid = threadIdx.x;
    float* Crow = ws + C_OFF + ((w - 1) * B_DIM + b) * T_DIM;

    if (cnt <= 0) {            // has_w == 0: window contributes nothing
        Crow[tid] = 0.f;
        return;
    }

    __shared__ float lp[T_DIM], lq[T_DIM], f1[T_DIM], f2[T_DIM];
    __shared__ float mi[T_DIM], ri[T_DIM], gg[T_DIM];
    __shared__ float red[8];

    lp[tid] = ws[P_OFF + b * T_DIM + tid];
    lq[tid] = ws[Q_OFF + b * T_DIM + tid];
    __syncthreads();

    float invw = 1.0f / (float)w;
    if (tid < cnt) {
        // tid + k <= cnt-1 + w-1 = turns <= 511, in-bounds and k_pq-written
        float s1 = lp[tid], s2 = lq[tid];
        for (int k = 1; k < w; ++k) { s1 += lp[tid + k]; s2 += lq[tid + k]; }
        f1[tid] = s1 * invw;
        f2[tid] = s2 * invw;
    } else {
        f2[tid] = -3.0e38f;
    }
    __syncthreads();

    // block max of f2 over valid entries (invalid filled with -3e38)
    float m = f2[tid];
    for (int off = 32; off > 0; off >>= 1) m = fmaxf(m, __shfl_down(m, off));
    if ((tid & 63) == 0) red[tid >> 6] = m;
    __syncthreads();
    if (tid == 0) {
        float mm = red[0];
        for (int i = 1; i < 8; ++i) mm = fmaxf(mm, red[i]);
        red[0] = mm;
    }
    __syncthreads();
    float M = red[0];

    // Pass A: per-row softmax max (analytic, lrelu monotone) + inverse row sum
    if (tid < cnt) {
        float f1i = f1[tid];
        float mrow = lrelu(f1i + M);
        float r = 0.f;
        for (int j = 0; j < cnt; ++j) {
            float s = lrelu(f1i + f2[j]);
            r += __expf(s - mrow);
        }
        mi[tid] = mrow;
        ri[tid] = 1.0f / r;
    }
    __syncthreads();

    // Pass B: column sums g[j] = (1/cnt) * sum_i exp(s_ij - m_i) / r_i
    float invcnt = 1.0f / (float)cnt;
    if (tid < cnt) {
        float f2j = f2[tid];
        float g = 0.f;
        for (int i = 0; i < cnt; ++i) {
            float s = lrelu(f1[i] + f2j);
            g += __expf(s - mi[i]) * ri[i];
        }
        gg[tid] = g * invcnt;
    } else {
        gg[tid] = 0.f;
    }
    __syncthreads();

    // x-row coefficient: c_t = (1/w) * sum_{k=0..w-1} g[t-k], t-k in [0,cnt)
    float coef = 0.f;
    for (int k = 0; k < w; ++k) {
        int j = tid - k;
        if (j >= 0) coef += gg[j];  // gg[j]=0 for j>=cnt
    }
    Crow[tid] = coef * invw;       // plain store, always written
}

// Kernel D: Zp[b][chunk][d] = sum_{t in chunk} C[b,t] * x[t,b,d].
// Grid 64*8 blocks x 256 threads, written unconditionally.
__global__ void k_z(const float* __restrict__ x, const int* __restrict__ turns,
                    float* __restrict__ ws) {
    int b = blockIdx.x >> 3;
    int chunk = blockIdx.x & 7;
    int tn = turns[b];
    int t0 = chunk * 64;
    int tid = threadIdx.x;  // d
    float acc = 0.f;
    if (t0 <= tn) {
        int t1 = min(t0 + 64, tn + 1);
        const float* C0 = ws + C_OFF + (0 * B_DIM + b) * T_DIM;
        const float* C1 = ws + C_OFF + (1 * B_DIM + b) * T_DIM;
        const float* C2 = ws + C_OFF + (2 * B_DIM + b) * T_DIM;
        for (int t = t0; t < t1; ++t) {
            float c = C0[t] + C1[t] + C2[t];
            acc += c * x[((size_t)t * B_DIM + b) * D_DIM + tid];
        }
    }
    ws[ZP_OFF + (b * 8 + chunk) * D_DIM + tid] = acc;
}

// Kernel E: out[b,:] = ((sum_chunk Zp[b][chunk]) @ W) / vws[b]. 64 blocks x 256 thr.
__global__ void k_out(const float* __restrict__ W, const int* __restrict__ turns,
                      const float* __restrict__ ws, float* __restrict__ out) {
    int b = blockIdx.x;
    int tid = threadIdx.x;  // d then f
    __shared__ float zz[D_DIM];
    const float* Zp = ws + ZP_OFF + b * 8 * D_DIM;
    float z = 0.f;
#pragma unroll
    for (int c = 0; c < 8; ++c) z += Zp[c * D_DIM + tid];
    zz[tid] = z;
    __syncthreads();
    float acc = 0.f;
#pragma unroll 4
    for (int d = 0; d < D_DIM; ++d)
        acc += zz[d] * W[(size_t)d * F_DIM + tid];
    int tn = turns[b];
    float vws = 1.0f + (tn >= 1 ? 1.0f : 0.0f) + (tn >= 2 ? 1.0f : 0.0f);
    out[b * F_DIM + tid] = acc / vws;
}

extern "C" void kernel_launch(void* const* d_in, const int* in_sizes, int n_in,
                              void* d_out, int out_size, void* d_ws, size_t ws_size,
                              hipStream_t stream) {
    const float* x = (const float*)d_in[0];     // (T,B,D) fp32
    const int* turns = (const int*)d_in[1];     // (B,) int32
    const float* W = (const float*)d_in[2];     // (D,F)
    const float* a1 = (const float*)d_in[3];    // (F,)
    const float* a2 = (const float*)d_in[4];    // (F,)
    float* out = (float*)d_out;                 // (B,F)
    float* ws = (float*)d_ws;

    k_uv<<<1, 256, 0, stream>>>(W, a1, a2, ws);
    k_pq<<<(B_DIM * T_DIM) / 4, 256, 0, stream>>>(x, turns, ws);
    k_attn<<<B_DIM * 3, 512, 0, stream>>>(turns, ws);
    k_z<<<B_DIM * 8, 256, 0, stream>>>(x, turns, ws);
    k_out<<<B_DIM, 256, 0, stream>>>(W, turns, ws, out);
}